// Round 3
// baseline (73.428 us; speedup 1.0000x reference)
//
#include <hip/hip_runtime.h>
#include <stdint.h>

#define OUT_F 8192
#define IN_F  8192
#define NGRP  1048576      // OUT*IN/GS
#define BATCH 64

typedef float f32x4 __attribute__((ext_vector_type(4)));
typedef _Float16 half8_t __attribute__((ext_vector_type(8)));

static __device__ __forceinline__ unsigned int pk_fma_f16(unsigned int a, unsigned int b, unsigned int c) {
  unsigned int d;
  asm("v_pk_fma_f16 %0, %1, %2, %3" : "=v"(d) : "v"(a), "v"(b), "v"(c));
  return d;
}

static __device__ __forceinline__ unsigned int pk16(float a, float b) {
  _Float16 ha = (_Float16)a, hb = (_Float16)b;
  unsigned short ua = __builtin_bit_cast(unsigned short, ha);
  unsigned short ub = __builtin_bit_cast(unsigned short, hb);
  return (unsigned int)ua | ((unsigned int)ub << 16);
}

// ---- pre-pass 1: x fp32 -> f16 ----
__global__ void cvt_x_kernel(const float* __restrict__ x, ushort* __restrict__ xh, int n4) {
  int i = blockIdx.x * blockDim.x + threadIdx.x;
  if (i < n4) {
    float4 v = ((const float4*)x)[i];
    ushort4 o;
    o.x = (ushort)__builtin_bit_cast(unsigned short, (_Float16)v.x);
    o.y = (ushort)__builtin_bit_cast(unsigned short, (_Float16)v.y);
    o.z = (ushort)__builtin_bit_cast(unsigned short, (_Float16)v.z);
    o.w = (ushort)__builtin_bit_cast(unsigned short, (_Float16)v.w);
    ((ushort4*)xh)[i] = o;
  }
}

// ---- pre-pass 2: per 2 groups pack {f16x2(s0,s1), f16x2(z'0,z'1)}, z' = -(64+z)*s ----
__global__ void pack_sz_kernel(const float* __restrict__ scale, const float* __restrict__ zero,
                               uint32_t* __restrict__ szb, int n4) {
  int i = blockIdx.x * blockDim.x + threadIdx.x;   // handles groups 4i..4i+3
  if (i < n4) {
    float4 s = ((const float4*)scale)[i];
    float4 z = ((const float4*)zero)[i];
    uint4 o;
    o.x = pk16(s.x, s.y);
    o.y = pk16(-(64.f + z.x) * s.x, -(64.f + z.y) * s.y);
    o.z = pk16(s.z, s.w);
    o.w = pk16(-(64.f + z.z) * s.z, -(64.f + z.w) * s.w);
    ((uint4*)szb)[i] = o;
  }
}

// ---- main fused dequant + GEMM, register-direct, no per-iter barriers ----
// grid 1024: c = bid>>3 (128), gq = (bid>>2)&1, ksb = bid&3.
// wave wid takes k-chunk ks = ksb*4+wid (512 k each, 16 steps of k32).
// lane tr = lane&15 owns Wq row gq*16+tr -> output rows g=gq*16+tr (hi) and g+32 (lo).
__global__ __launch_bounds__(256, 4) void hqq_gemm_kernel(
    const int* __restrict__ Wq, const uint32_t* __restrict__ szb,
    const ushort* __restrict__ xh, float* __restrict__ part)
{
  const int t    = threadIdx.x;
  const int bid  = blockIdx.x;
  const int c    = bid >> 3;
  const int gq   = (bid >> 2) & 1;
  const int ksb  = bid & 3;
  const int wid  = t >> 6;
  const int lane = t & 63;
  const int tr   = lane & 15;
  const int koff = (lane >> 4) * 8;

  const int ks    = ksb * 4 + wid;
  const int kbase = ks * 512;

  const int* __restrict__ wqp =
      Wq + (size_t)(gq * 16 + tr) * NGRP + (size_t)c * IN_F + kbase + koff;
  const uint4* __restrict__ szp4 =
      (const uint4*)szb + (((size_t)c * IN_F + kbase + koff) >> 2);
  const ushort* __restrict__ xrow0 = xh + (size_t)tr * IN_F + kbase + koff;

  f32x4 acc[2][4];
  #pragma unroll
  for (int n = 0; n < 2; ++n)
    #pragma unroll
    for (int m = 0; m < 4; ++m)
      acc[n][m] = (f32x4){0.f, 0.f, 0.f, 0.f};

  // depth-2 register prefetch ring
  uint4 rWa[2], rWb[2], rSa[2], rSb[2];
  #define LOADSTEP(s, itv)                                         \
    do {                                                           \
      rWa[s] = *(const uint4*)(wqp + (itv) * 32);                  \
      rWb[s] = *(const uint4*)(wqp + (itv) * 32 + 4);              \
      rSa[s] = szp4[(itv) * 8];                                    \
      rSb[s] = szp4[(itv) * 8 + 1];                                \
    } while (0)

  LOADSTEP(0, 0);
  LOADSTEP(1, 1);

  #pragma unroll
  for (int it = 0; it < 16; ++it) {
    const int s = it & 1;
    const uint4 Wl = rWa[s], Wh = rWb[s], Sl = rSa[s], Sh = rSb[s];
    if (it + 2 < 16) LOADSTEP(s, it + 2);

    const unsigned int w8[8] = {Wl.x, Wl.y, Wl.z, Wl.w, Wh.x, Wh.y, Wh.z, Wh.w};
    const unsigned int sp[4] = {Sl.x, Sl.z, Sh.x, Sh.z};
    const unsigned int zp[4] = {Sl.y, Sl.w, Sh.y, Sh.w};

    union { uint4 u; half8_t h; } ub0, ub1;
    unsigned int b0[4], b1[4];
    #pragma unroll
    for (int j = 0; j < 4; ++j) {
      // w values are 0..255 (int32 holding one packed byte): no masking needed
      const unsigned int tt = (w8[2 * j + 1] << 16) | w8[2 * j];
      const unsigned int hb = (tt & 0x00F000F0u) | 0x54005400u;         // f16 pair 64+hi
      const unsigned int lb = ((tt << 4) & 0x00F000F0u) | 0x54005400u;  // f16 pair 64+lo
      b0[j] = pk_fma_f16(hb, sp[j], zp[j]);
      b1[j] = pk_fma_f16(lb, sp[j], zp[j]);
    }
    ub0.u.x = b0[0]; ub0.u.y = b0[1]; ub0.u.z = b0[2]; ub0.u.w = b0[3];
    ub1.u.x = b1[0]; ub1.u.y = b1[1]; ub1.u.z = b1[2]; ub1.u.w = b1[3];
    const half8_t vb0 = ub0.h;
    const half8_t vb1 = ub1.h;

    const int kcol = it * 32;
    #pragma unroll
    for (int mq = 0; mq < 4; ++mq) {
      const half8_t a = *(const half8_t*)(xrow0 + (size_t)mq * 16 * IN_F + kcol);
      acc[0][mq] = __builtin_amdgcn_mfma_f32_16x16x32_f16(a, vb0, acc[0][mq], 0, 0, 0);
      acc[1][mq] = __builtin_amdgcn_mfma_f32_16x16x32_f16(a, vb1, acc[1][mq], 0, 0, 0);
    }
  }
  #undef LOADSTEP

  // ---- in-block reduction across the 4 k-chunk waves (single barrier) ----
  __shared__ float red[4][2048];
  #pragma unroll
  for (int nib = 0; nib < 2; ++nib)
    #pragma unroll
    for (int mq = 0; mq < 4; ++mq)
      #pragma unroll
      for (int j = 0; j < 4; ++j)
        red[wid][(nib * 16 + mq * 4 + j) * 64 + lane] = acc[nib][mq][j];
  __syncthreads();

  float* pp = part + (size_t)ksb * (BATCH * OUT_F);
  #pragma unroll
  for (int q = 0; q < 8; ++q) {
    const int idx = q * 256 + t;
    const float v = red[0][idx] + red[1][idx] + red[2][idx] + red[3][idx];
    const int r    = idx >> 6;
    const int lsrc = idx & 63;
    const int nib  = r >> 4;
    const int mq   = (r >> 2) & 3;
    const int j    = r & 3;
    const int m = mq * 16 + (lsrc >> 4) * 4 + j;
    const int o = (gq * 16 + (lsrc & 15)) * 128 + c + nib * 4096;
    pp[(size_t)m * OUT_F + o] = v;
  }
}

// ---- split-K reduction (+bias), deterministic ----
__global__ __launch_bounds__(256) void reduce_kernel(const float* __restrict__ part,
                                                     const float* __restrict__ bias,
                                                     float* __restrict__ out)
{
  int i = blockIdx.x * blockDim.x + threadIdx.x;   // float4 index, 131072 total
  float4 a = ((const float4*)part)[i];
  float4 b = ((const float4*)(part + (size_t)1 * BATCH * OUT_F))[i];
  float4 c = ((const float4*)(part + (size_t)2 * BATCH * OUT_F))[i];
  float4 d = ((const float4*)(part + (size_t)3 * BATCH * OUT_F))[i];
  int o = (i * 4) & (OUT_F - 1);
  float4 bv = *(const float4*)(bias + o);
  float4 r;
  r.x = a.x + b.x + c.x + d.x + bv.x;
  r.y = a.y + b.y + c.y + d.y + bv.y;
  r.z = a.z + b.z + c.z + d.z + bv.z;
  r.w = a.w + b.w + c.w + d.w + bv.w;
  ((float4*)out)[i] = r;
}

// ---- correctness fallback (tiny ws), fp32 ----
__global__ void hqq_fallback_kernel(const float* __restrict__ x, const int* __restrict__ Wq,
                                    const float* __restrict__ scale, const float* __restrict__ zero,
                                    const float* __restrict__ bias, float* __restrict__ out)
{
  int idx = blockIdx.x * blockDim.x + threadIdx.x;
  int b = idx >> 13;
  int o = idx & 8191;
  int g = o >> 7, cc = o & 127;
  int r = g & 31;
  bool hi = (g < 32);
  const int*   wrow = Wq    + (size_t)r  * NGRP + (size_t)cc * IN_F;
  const float* srow = scale + (size_t)cc * IN_F;
  const float* zrow = zero  + (size_t)cc * IN_F;
  const float* xrow = x     + (size_t)b  * IN_F;
  float acc = 0.f;
  for (int k = 0; k < IN_F; ++k) {
    int v = wrow[k];
    float nib = (float)(hi ? (v >> 4) : (v & 15));
    acc += xrow[k] * ((nib - zrow[k]) * srow[k]);
  }
  out[idx] = acc + bias[o];
}

extern "C" void kernel_launch(void* const* d_in, const int* in_sizes, int n_in,
                              void* d_out, int out_size, void* d_ws, size_t ws_size,
                              hipStream_t stream) {
  const float* x     = (const float*)d_in[0];
  const int*   Wq    = (const int*)d_in[1];
  const float* scale = (const float*)d_in[2];
  const float* zero  = (const float*)d_in[3];
  const float* bias  = (const float*)d_in[4];
  float* out = (float*)d_out;

  const size_t xh_bytes   = (size_t)BATCH * IN_F * sizeof(ushort);        // 1 MB
  const size_t sz_bytes   = (size_t)(NGRP / 2) * 8;                       // 4 MB
  const size_t part_bytes = (size_t)4 * BATCH * OUT_F * sizeof(float);    // 8 MB

  if (ws_size >= xh_bytes + sz_bytes + part_bytes) {
    ushort*   xh   = (ushort*)d_ws;
    uint32_t* szb  = (uint32_t*)((char*)d_ws + xh_bytes);
    float*    part = (float*)((char*)d_ws + xh_bytes + sz_bytes);
    cvt_x_kernel<<<(BATCH * IN_F / 4) / 256, 256, 0, stream>>>(x, xh, BATCH * IN_F / 4);
    pack_sz_kernel<<<(NGRP / 4) / 256, 256, 0, stream>>>(scale, zero, szb, NGRP / 4);
    hqq_gemm_kernel<<<1024, 256, 0, stream>>>(Wq, szb, xh, part);
    reduce_kernel<<<(BATCH * OUT_F / 4) / 256, 256, 0, stream>>>(part, bias, out);
  } else {
    hqq_fallback_kernel<<<(BATCH * OUT_F) / 256, 256, 0, stream>>>(x, Wq, scale, zero, bias, out);
  }
}

// Round 5
// 51.993 us; speedup vs baseline: 1.4123x; 1.4123x over previous
//
#include <hip/hip_runtime.h>
#include <stdint.h>

#define OUT_F 8192
#define IN_F  8192
#define NGRP  1048576      // OUT*IN/GS
#define BATCH 64
#define KS    4
#define NSTEP 16           // (IN_F/KS)/128

typedef float f32x4 __attribute__((ext_vector_type(4)));
typedef _Float16 half8_t __attribute__((ext_vector_type(8)));

static __device__ __forceinline__ unsigned int pk_fma_f16(unsigned int a, unsigned int b, unsigned int c) {
  unsigned int d;
  asm("v_pk_fma_f16 %0, %1, %2, %3" : "=v"(d) : "v"(a), "v"(b), "v"(c));
  return d;
}
static __device__ __forceinline__ unsigned int pk16(float a, float b) {
  unsigned short ua = __builtin_bit_cast(unsigned short, (_Float16)a);
  unsigned short ub = __builtin_bit_cast(unsigned short, (_Float16)b);
  return (unsigned int)ua | ((unsigned int)ub << 16);
}

#define GLL16(g, l)                                                         \
  __builtin_amdgcn_global_load_lds(                                         \
      (const __attribute__((address_space(1))) void*)(g),                   \
      (__attribute__((address_space(3))) void*)(l), 16, 0, 0)

// ---- pre-pass 1: x fp32 -> f16 ----
__global__ void cvt_x_kernel(const float* __restrict__ x, ushort* __restrict__ xh, int n4) {
  int i = blockIdx.x * blockDim.x + threadIdx.x;
  if (i < n4) {
    float4 v = ((const float4*)x)[i];
    ushort4 o;
    o.x = __builtin_bit_cast(unsigned short, (_Float16)v.x);
    o.y = __builtin_bit_cast(unsigned short, (_Float16)v.y);
    o.z = __builtin_bit_cast(unsigned short, (_Float16)v.z);
    o.w = __builtin_bit_cast(unsigned short, (_Float16)v.w);
    ((ushort4*)xh)[i] = o;
  }
}

// ---- pre-pass 2: per 2 groups pack {f16x2(s0,s1), f16x2(z'0,z'1)}, z' = -(64+z)*s ----
__global__ void pack_sz_kernel(const float* __restrict__ scale, const float* __restrict__ zero,
                               uint32_t* __restrict__ szb, int n4) {
  int i = blockIdx.x * blockDim.x + threadIdx.x;
  if (i < n4) {
    float4 s = ((const float4*)scale)[i];
    float4 z = ((const float4*)zero)[i];
    uint4 o;
    o.x = pk16(s.x, s.y);
    o.y = pk16(-(64.f + z.x) * s.x, -(64.f + z.y) * s.y);
    o.z = pk16(s.z, s.w);
    o.w = pk16(-(64.f + z.z) * s.z, -(64.f + z.w) * s.w);
    ((uint4*)szb)[i] = o;
  }
}

// ---- main fused dequant + GEMM ----
// grid 1024: ks = bid&3 (split-K, 2048 k each), gq = (bid>>2)&1 (16 Wq rows), c = bid>>3.
// Per step (128 k): x-tile [64m][128k] f16 via global_load_lds (content-swizzled source),
// B-tile [32][128] f16 reg-staged + dequant-fused (rows 0..15 hi nibble, 16..31 lo).
__global__ __launch_bounds__(256, 3) void hqq_gemm_kernel(
    const int* __restrict__ Wq, const uint32_t* __restrict__ szb,
    const ushort* __restrict__ xh, float* __restrict__ part)
{
  __shared__ ushort xlds[2][64 * 128];   // 16 KB each
  __shared__ ushort blds[2][32 * 128];   // 8 KB each

  const int t    = threadIdx.x;
  const int bid  = blockIdx.x;
  const int ks   = bid & 3;
  const int gq   = (bid >> 2) & 1;
  const int c    = bid >> 3;
  const int lane = t & 63;
  const int wid  = t >> 6;
  const int kbase = ks * (IN_F / KS);

  // staging ids: 16 Wq rows x 16 k-octets
  const int sr  = t >> 4;   // 0..15
  const int skq = t & 15;   // 0..15
  const int* __restrict__ wqp =
      Wq + (size_t)(gq * 16 + sr) * NGRP + (size_t)c * IN_F + kbase + skq * 8;
  const uint8_t* __restrict__ szp =
      (const uint8_t*)szb + ((size_t)c * IN_F + kbase + skq * 8) * 4;
  const int wbyte = (skq * 16) ^ ((sr & 7) << 4);   // swizzled B write col

  // frag ids
  const int tr    = lane & 15;
  const int koff8 = (lane >> 4) * 8;
  const int am    = wid * 16 + tr;                  // A row (m)

  f32x4 acc_h = {0.f, 0.f, 0.f, 0.f};
  f32x4 acc_l = {0.f, 0.f, 0.f, 0.f};

  // issue x staging for step s (4 gll per wave); source pre-swizzled so LDS
  // linear layout == swizzled content: LDS[m][b] = x[m][b ^ ((m&7)<<4)]
  auto stage_x = [&](int s) {
    const int b = s & 1;
    #pragma unroll
    for (int j = 0; j < 4; ++j) {
      const int m    = wid * 16 + j * 4 + (lane >> 4);
      const int bcol = (lane & 15) * 16;
      const int scol = bcol ^ ((m & 7) << 4);
      const ushort* g = xh + (size_t)m * IN_F + kbase + s * 128 + (scol >> 1);
      ushort* l = &xlds[b][(wid * 16 + j * 4) * 128];   // wave-uniform base
      GLL16(g, l);
    }
  };

  // dequant + write B tile for step s from preloaded regs.
  // f16 magic: 0x5400 | (v<<4) == 64+v  (nibble must land at mantissa bits [7:4]).
  auto stage_b = [&](int s, const int4& wa, const int4& wb, const uint4& sa, const uint4& sb) {
    uint8_t* bb = (uint8_t*)&blds[s & 1][0];
    uint4 hi4, lo4;
    {
      unsigned tt = ((unsigned)wa.y << 16) | (unsigned)wa.x;
      hi4.x = pk_fma_f16((tt & 0x00F000F0u) | 0x54005400u, sa.x, sa.y);        // hi nibble @ [7:4]
      lo4.x = pk_fma_f16(((tt << 4) & 0x00F000F0u) | 0x54005400u, sa.x, sa.y); // lo nibble -> [7:4]
    }
    {
      unsigned tt = ((unsigned)wa.w << 16) | (unsigned)wa.z;
      hi4.y = pk_fma_f16((tt & 0x00F000F0u) | 0x54005400u, sa.z, sa.w);
      lo4.y = pk_fma_f16(((tt << 4) & 0x00F000F0u) | 0x54005400u, sa.z, sa.w);
    }
    {
      unsigned tt = ((unsigned)wb.y << 16) | (unsigned)wb.x;
      hi4.z = pk_fma_f16((tt & 0x00F000F0u) | 0x54005400u, sb.x, sb.y);
      lo4.z = pk_fma_f16(((tt << 4) & 0x00F000F0u) | 0x54005400u, sb.x, sb.y);
    }
    {
      unsigned tt = ((unsigned)wb.w << 16) | (unsigned)wb.z;
      hi4.w = pk_fma_f16((tt & 0x00F000F0u) | 0x54005400u, sb.z, sb.w);
      lo4.w = pk_fma_f16(((tt << 4) & 0x00F000F0u) | 0x54005400u, sb.z, sb.w);
    }
    *(uint4*)(bb + sr * 256 + wbyte)        = hi4;   // hi nibble rows 0..15
    *(uint4*)(bb + (sr + 16) * 256 + wbyte) = lo4;   // lo nibble rows 16..31
  };

  // prologue: stage step 0
  stage_x(0);
  {
    int4  wa = *(const int4*)(wqp);
    int4  wb = *(const int4*)(wqp + 4);
    uint4 sa = *(const uint4*)(szp);
    uint4 sb = *(const uint4*)(szp + 16);
    stage_b(0, wa, wb, sa, sb);
  }
  __syncthreads();

  #pragma unroll 2
  for (int s = 0; s < NSTEP; ++s) {
    int4  wa, wb;
    uint4 sa, sb;
    const bool more = (s + 1 < NSTEP);
    if (more) {
      stage_x(s + 1);                                     // async -> LDS (vmcnt)
      wa = *(const int4*)(wqp + (s + 1) * 128);           // reg loads, consumed late
      wb = *(const int4*)(wqp + (s + 1) * 128 + 4);
      sa = *(const uint4*)(szp + (size_t)(s + 1) * 512);
      sb = *(const uint4*)(szp + (size_t)(s + 1) * 512 + 16);
    }

    // compute on buf s&1: pure ds_read + MFMA
    const uint8_t* xb = (const uint8_t*)&xlds[s & 1][0];
    const uint8_t* bb = (const uint8_t*)&blds[s & 1][0];
    #pragma unroll
    for (int kk = 0; kk < 4; ++kk) {
      const int colb = (koff8 + kk * 32) * 2;
      half8_t a   = *(const half8_t*)(xb + am * 256 + (colb ^ ((am & 7) << 4)));
      half8_t bhi = *(const half8_t*)(bb + tr * 256 + (colb ^ ((tr & 7) << 4)));
      half8_t blo = *(const half8_t*)(bb + (tr + 16) * 256 + (colb ^ ((tr & 7) << 4)));
      acc_h = __builtin_amdgcn_mfma_f32_16x16x32_f16(a, bhi, acc_h, 0, 0, 0);
      acc_l = __builtin_amdgcn_mfma_f32_16x16x32_f16(a, blo, acc_l, 0, 0, 0);
    }

    if (more) stage_b(s + 1, wa, wb, sa, sb);   // consume regs after compute
    __syncthreads();                             // drains vmcnt (gll) + lgkmcnt
  }

  // epilogue: C/D col = lane&15 -> o, row = (lane>>4)*4 + j -> m
  const int o_hi = (gq * 16 + tr) * 128 + c;
  const int m0   = wid * 16 + (lane >> 4) * 4;
  float* p_hi = part + ((size_t)ks * OUT_F + o_hi) * BATCH + m0;
  float* p_lo = part + ((size_t)ks * OUT_F + o_hi + 4096) * BATCH + m0;
  *(float4*)p_hi = (float4){acc_h[0], acc_h[1], acc_h[2], acc_h[3]};
  *(float4*)p_lo = (float4){acc_l[0], acc_l[1], acc_l[2], acc_l[3]};
}

// ---- split-K reduce + bias + transpose to out[m][o] ----
__global__ __launch_bounds__(256) void reduce_kernel(const float* __restrict__ part,
                                                     const float* __restrict__ bias,
                                                     float* __restrict__ out)
{
  __shared__ float tile[32][65];
  const int ob = blockIdx.x;          // o-range [ob*32, +32)
  const int t  = threadIdx.x;
  {
    const int ol = t >> 3;            // 0..31
    const int mg = t & 7;             // m-octet
    const int o  = ob * 32 + ol;
    const size_t base = (size_t)o * BATCH + mg * 8;
    float s[8] = {0, 0, 0, 0, 0, 0, 0, 0};
    #pragma unroll
    for (int ks = 0; ks < KS; ++ks) {
      const float* p = part + (size_t)ks * OUT_F * BATCH + base;
      float4 a = *(const float4*)p;
      float4 b = *(const float4*)(p + 4);
      s[0] += a.x; s[1] += a.y; s[2] += a.z; s[3] += a.w;
      s[4] += b.x; s[5] += b.y; s[6] += b.z; s[7] += b.w;
    }
    const float bv = bias[o];
    #pragma unroll
    for (int j = 0; j < 8; ++j) tile[ol][mg * 8 + j] = s[j] + bv;
  }
  __syncthreads();
  {
    const int m  = t >> 2;            // 0..63
    const int og = (t & 3) * 8;       // 0..31
    float r[8];
    #pragma unroll
    for (int j = 0; j < 8; ++j) r[j] = tile[og + j][m];
    float* op = out + (size_t)m * OUT_F + ob * 32 + og;
    *(float4*)op       = (float4){r[0], r[1], r[2], r[3]};
    *(float4*)(op + 4) = (float4){r[4], r[5], r[6], r[7]};
  }
}

// ---- correctness fallback (tiny ws), fp32 ----
__global__ void hqq_fallback_kernel(const float* __restrict__ x, const int* __restrict__ Wq,
                                    const float* __restrict__ scale, const float* __restrict__ zero,
                                    const float* __restrict__ bias, float* __restrict__ out)
{
  int idx = blockIdx.x * blockDim.x + threadIdx.x;
  int b = idx >> 13;
  int o = idx & 8191;
  int g = o >> 7, cc = o & 127;
  int r = g & 31;
  bool hi = (g < 32);
  const int*   wrow = Wq    + (size_t)r  * NGRP + (size_t)cc * IN_F;
  const float* srow = scale + (size_t)cc * IN_F;
  const float* zrow = zero  + (size_t)cc * IN_F;
  const float* xrow = x     + (size_t)b  * IN_F;
  float acc = 0.f;
  for (int k = 0; k < IN_F; ++k) {
    int v = wrow[k];
    float nib = (float)(hi ? (v >> 4) : (v & 15));
    acc += xrow[k] * ((nib - zrow[k]) * srow[k]);
  }
  out[idx] = acc + bias[o];
}

extern "C" void kernel_launch(void* const* d_in, const int* in_sizes, int n_in,
                              void* d_out, int out_size, void* d_ws, size_t ws_size,
                              hipStream_t stream) {
  const float* x     = (const float*)d_in[0];
  const int*   Wq    = (const int*)d_in[1];
  const float* scale = (const float*)d_in[2];
  const float* zero  = (const float*)d_in[3];
  const float* bias  = (const float*)d_in[4];
  float* out = (float*)d_out;

  const size_t xh_bytes   = (size_t)BATCH * IN_F * sizeof(ushort);        // 1 MB
  const size_t sz_bytes   = (size_t)NGRP * 4;                             // 4 MB
  const size_t part_bytes = (size_t)KS * BATCH * OUT_F * sizeof(float);   // 8 MB

  if (ws_size >= xh_bytes + sz_bytes + part_bytes) {
    ushort*   xh   = (ushort*)d_ws;
    uint32_t* szb  = (uint32_t*)((char*)d_ws + xh_bytes);
    float*    part = (float*)((char*)d_ws + xh_bytes + sz_bytes);
    cvt_x_kernel<<<(BATCH * IN_F / 4) / 256, 256, 0, stream>>>(x, xh, BATCH * IN_F / 4);
    pack_sz_kernel<<<(NGRP / 4) / 256, 256, 0, stream>>>(scale, zero, szb, NGRP / 4);
    hqq_gemm_kernel<<<128 * 2 * KS, 256, 0, stream>>>(Wq, szb, xh, part);
    reduce_kernel<<<OUT_F / 32, 256, 0, stream>>>(part, bias, out);
  } else {
    hqq_fallback_kernel<<<(BATCH * OUT_F) / 256, 256, 0, stream>>>(x, Wq, scale, zero, bias, out);
  }
}

// Round 6
// 47.050 us; speedup vs baseline: 1.5606x; 1.1051x over previous
//
#include <hip/hip_runtime.h>
#include <stdint.h>

#define OUT_F 8192
#define IN_F  8192
#define NGRP  1048576      // OUT*IN/GS
#define BATCH 64
#define KS    2
#define NSTEP ((IN_F / KS) / 128)   // 32

typedef float f32x4 __attribute__((ext_vector_type(4)));
typedef _Float16 half8_t __attribute__((ext_vector_type(8)));

static __device__ __forceinline__ unsigned int pk_fma_f16(unsigned int a, unsigned int b, unsigned int c) {
  unsigned int d;
  asm("v_pk_fma_f16 %0, %1, %2, %3" : "=v"(d) : "v"(a), "v"(b), "v"(c));
  return d;
}
static __device__ __forceinline__ unsigned int pk16(float a, float b) {
  unsigned short ua = __builtin_bit_cast(unsigned short, (_Float16)a);
  unsigned short ub = __builtin_bit_cast(unsigned short, (_Float16)b);
  return (unsigned int)ua | ((unsigned int)ub << 16);
}

#define GLL16(g, l)                                                         \
  __builtin_amdgcn_global_load_lds(                                         \
      (const __attribute__((address_space(1))) void*)(g),                   \
      (__attribute__((address_space(3))) void*)(l), 16, 0, 0)

// ---- fused pre-pass: x fp32->f16  +  per-2-group {f16x2(s), f16x2(-(64+z)s)} ----
__global__ __launch_bounds__(256) void pre_kernel(const float* __restrict__ x, ushort* __restrict__ xh,
                                                  const float* __restrict__ scale, const float* __restrict__ zero,
                                                  uint32_t* __restrict__ szb) {
  const int b = blockIdx.x;
  if (b < 512) {                      // 512*256 = 131072 = BATCH*IN_F/4
    const int i = b * 256 + threadIdx.x;
    float4 v = ((const float4*)x)[i];
    ushort4 o;
    o.x = __builtin_bit_cast(unsigned short, (_Float16)v.x);
    o.y = __builtin_bit_cast(unsigned short, (_Float16)v.y);
    o.z = __builtin_bit_cast(unsigned short, (_Float16)v.z);
    o.w = __builtin_bit_cast(unsigned short, (_Float16)v.w);
    ((ushort4*)xh)[i] = o;
  } else {                            // 1024*256 = 262144 = NGRP/4
    const int i = (b - 512) * 256 + threadIdx.x;
    float4 s = ((const float4*)scale)[i];
    float4 z = ((const float4*)zero)[i];
    uint4 o;
    o.x = pk16(s.x, s.y);
    o.y = pk16(-(64.f + z.x) * s.x, -(64.f + z.y) * s.y);
    o.z = pk16(s.z, s.w);
    o.w = pk16(-(64.f + z.z) * s.z, -(64.f + z.w) * s.w);
    ((uint4*)szb)[i] = o;
  }
}

// ---- main fused dequant + GEMM, depth-3 counted-vmcnt pipeline ----
// grid 512: ks = bid&1 (4096 k each), gq = (bid>>1)&1 (16 Wq rows), c = bid>>2.
// x: wave-private rows, triple-buffered LDS via global_load_lds (no barrier needed).
// B: [32][128] f16, dequant-fused reg->LDS staging, double-buffered, 1 raw barrier/step.
__global__ __launch_bounds__(256, 2) void hqq_gemm_kernel(
    const int* __restrict__ Wq, const uint32_t* __restrict__ szb,
    const ushort* __restrict__ xh, float* __restrict__ part)
{
  __shared__ ushort xlds[3][64 * 128];   // 16 KB each
  __shared__ ushort blds[2][32 * 128];   // 8 KB each

  const int t    = threadIdx.x;
  const int bid  = blockIdx.x;
  const int ks   = bid & 1;
  const int gq   = (bid >> 1) & 1;
  const int c    = bid >> 2;
  const int lane = t & 63;
  const int wid  = t >> 6;
  const int kbase = ks * (IN_F / KS);

  // B staging ids: 16 Wq rows x 16 k-octets
  const int sr  = t >> 4;   // 0..15
  const int skq = t & 15;   // 0..15
  const int* __restrict__ wqp =
      Wq + (size_t)(gq * 16 + sr) * NGRP + (size_t)c * IN_F + kbase + skq * 8;
  const uint8_t* __restrict__ szp =
      (const uint8_t*)szb + ((size_t)c * IN_F + kbase + skq * 8) * 4;
  const int wbyte = (skq * 16) ^ ((sr & 7) << 4);

  // frag ids
  const int tr    = lane & 15;
  const int koff8 = (lane >> 4) * 8;
  const int am    = wid * 16 + tr;

  f32x4 acc_h = {0.f, 0.f, 0.f, 0.f};
  f32x4 acc_l = {0.f, 0.f, 0.f, 0.f};

  // 4 gll; wave-private rows wid*16..+15; source pre-swizzled so that
  // LDS[m][b] = x[m][b ^ ((m&7)<<4)]
  auto stage_x = [&](int bi, int s) {
    #pragma unroll
    for (int j = 0; j < 4; ++j) {
      const int m    = wid * 16 + j * 4 + (lane >> 4);
      const int bcol = (lane & 15) * 16;
      const int scol = bcol ^ ((m & 7) << 4);
      const ushort* g = xh + (size_t)m * IN_F + kbase + s * 128 + (scol >> 1);
      ushort* l = &xlds[bi][(wid * 16 + j * 4) * 128];
      GLL16(g, l);
    }
  };

  auto ldregs = [&](int s, int4& wa, int4& wb, uint4& sa, uint4& sb) {
    wa = *(const int4*)(wqp + (size_t)s * 128);
    wb = *(const int4*)(wqp + (size_t)s * 128 + 4);
    sa = *(const uint4*)(szp + (size_t)s * 512);
    sb = *(const uint4*)(szp + (size_t)s * 512 + 16);
  };

  // f16 magic: 0x5400 | (v<<4) == 64+v  (nibble at mantissa bits [7:4])
  auto stage_b = [&](int bi, const int4& wa, const int4& wb, const uint4& sa, const uint4& sb) {
    uint8_t* bb = (uint8_t*)&blds[bi][0];
    uint4 hi4, lo4;
    {
      unsigned tt = ((unsigned)wa.y << 16) | (unsigned)wa.x;
      hi4.x = pk_fma_f16((tt & 0x00F000F0u) | 0x54005400u, sa.x, sa.y);
      lo4.x = pk_fma_f16(((tt << 4) & 0x00F000F0u) | 0x54005400u, sa.x, sa.y);
    }
    {
      unsigned tt = ((unsigned)wa.w << 16) | (unsigned)wa.z;
      hi4.y = pk_fma_f16((tt & 0x00F000F0u) | 0x54005400u, sa.z, sa.w);
      lo4.y = pk_fma_f16(((tt << 4) & 0x00F000F0u) | 0x54005400u, sa.z, sa.w);
    }
    {
      unsigned tt = ((unsigned)wb.y << 16) | (unsigned)wb.x;
      hi4.z = pk_fma_f16((tt & 0x00F000F0u) | 0x54005400u, sb.x, sb.y);
      lo4.z = pk_fma_f16(((tt << 4) & 0x00F000F0u) | 0x54005400u, sb.x, sb.y);
    }
    {
      unsigned tt = ((unsigned)wb.w << 16) | (unsigned)wb.z;
      hi4.w = pk_fma_f16((tt & 0x00F000F0u) | 0x54005400u, sb.z, sb.w);
      lo4.w = pk_fma_f16(((tt << 4) & 0x00F000F0u) | 0x54005400u, sb.z, sb.w);
    }
    *(uint4*)(bb + sr * 256 + wbyte)        = hi4;
    *(uint4*)(bb + (sr + 16) * 256 + wbyte) = lo4;
  };

  // ---- prologue ----
  {
    int4 wa0, wb0; uint4 sa0, sb0;
    ldregs(0, wa0, wb0, sa0, sb0);
    stage_b(0, wa0, wb0, sa0, sb0);   // compiler waits for regs(0)
  }
  stage_x(0, 0);
  stage_x(1, 1);
  int4 wa, wb; uint4 sa, sb;
  ldregs(1, wa, wb, sa, sb);          // regs for stage_b(1)

  int xr0 = 0, xr1 = 1, xr2 = 2;

  #pragma unroll 1
  for (int s = 0; s < NSTEP; ++s) {
    // retire compute(s-1) on all waves; make stage_b(s) ds_writes visible.
    // Raw barrier: does NOT drain vmcnt -> prefetches stay in flight.
    asm volatile("s_waitcnt lgkmcnt(0)" ::: "memory");
    __builtin_amdgcn_s_barrier();

    const bool more2 = (s + 2 < NSTEP);
    int4 nwa, nwb; uint4 nsa, nsb;
    if (more2) {
      stage_x(xr2, s + 2);            // 4 gll (buffer freed by barrier above)
      ldregs(s + 2, nwa, nwb, nsa, nsb);  // 4 dwordx4, consumed next iter
    }

    // wait for x(s) glls: issued 2 iters ago; 16 newer vmem ops outstanding
    // (x(s+1)+regs(s+1)+x(s+2)+regs(s+2)); in-order vmcnt retire => done.
    if (more2)               asm volatile("s_waitcnt vmcnt(16)" ::: "memory");
    else if (s + 1 < NSTEP)  asm volatile("s_waitcnt vmcnt(8)" ::: "memory");
    else                     asm volatile("s_waitcnt vmcnt(0)" ::: "memory");
    __builtin_amdgcn_sched_barrier(0);

    // compute(s): pure ds_read + MFMA on xlds[xr0], blds[s&1]
    const uint8_t* xb = (const uint8_t*)&xlds[xr0][0];
    const uint8_t* bb = (const uint8_t*)&blds[s & 1][0];
    #pragma unroll
    for (int kk = 0; kk < 4; ++kk) {
      const int colb = (koff8 + kk * 32) * 2;
      half8_t a   = *(const half8_t*)(xb + am * 256 + (colb ^ ((am & 7) << 4)));
      half8_t bhi = *(const half8_t*)(bb + tr * 256 + (colb ^ ((tr & 7) << 4)));
      half8_t blo = *(const half8_t*)(bb + (tr + 16) * 256 + (colb ^ ((tr & 7) << 4)));
      acc_h = __builtin_amdgcn_mfma_f32_16x16x32_f16(a, bhi, acc_h, 0, 0, 0);
      acc_l = __builtin_amdgcn_mfma_f32_16x16x32_f16(a, blo, acc_l, 0, 0, 0);
    }

    // dequant + ds_write B(s+1); compiler inserts counted vmcnt for regs(s+1)
    if (s + 1 < NSTEP) stage_b((s + 1) & 1, wa, wb, sa, sb);
    if (more2) { wa = nwa; wb = nwb; sa = nsa; sb = nsb; }

    const int tmp = xr0; xr0 = xr1; xr1 = xr2; xr2 = tmp;
  }

  // epilogue: C/D col = lane&15 -> o, row = (lane>>4)*4 + j -> m
  const int o_hi = (gq * 16 + tr) * 128 + c;
  const int m0   = wid * 16 + (lane >> 4) * 4;
  float* p_hi = part + ((size_t)ks * OUT_F + o_hi) * BATCH + m0;
  float* p_lo = part + ((size_t)ks * OUT_F + o_hi + 4096) * BATCH + m0;
  *(float4*)p_hi = (float4){acc_h[0], acc_h[1], acc_h[2], acc_h[3]};
  *(float4*)p_lo = (float4){acc_l[0], acc_l[1], acc_l[2], acc_l[3]};
}

// ---- split-K reduce + bias + transpose to out[m][o] ----
__global__ __launch_bounds__(256) void reduce_kernel(const float* __restrict__ part,
                                                     const float* __restrict__ bias,
                                                     float* __restrict__ out)
{
  __shared__ float tile[32][65];
  const int ob = blockIdx.x;          // o-range [ob*32, +32)
  const int t  = threadIdx.x;
  {
    const int ol = t >> 3;            // 0..31
    const int mg = t & 7;             // m-octet
    const int o  = ob * 32 + ol;
    const size_t base = (size_t)o * BATCH + mg * 8;
    float s[8] = {0, 0, 0, 0, 0, 0, 0, 0};
    #pragma unroll
    for (int ks = 0; ks < KS; ++ks) {
      const float* p = part + (size_t)ks * OUT_F * BATCH + base;
      float4 a = *(const float4*)p;
      float4 b = *(const float4*)(p + 4);
      s[0] += a.x; s[1] += a.y; s[2] += a.z; s[3] += a.w;
      s[4] += b.x; s[5] += b.y; s[6] += b.z; s[7] += b.w;
    }
    const float bv = bias[o];
    #pragma unroll
    for (int j = 0; j < 8; ++j) tile[ol][mg * 8 + j] = s[j] + bv;
  }
  __syncthreads();
  {
    const int m  = t >> 2;            // 0..63
    const int og = (t & 3) * 8;       // 0..31
    float r[8];
    #pragma unroll
    for (int j = 0; j < 8; ++j) r[j] = tile[og + j][m];
    float* op = out + (size_t)m * OUT_F + ob * 32 + og;
    *(float4*)op       = (float4){r[0], r[1], r[2], r[3]};
    *(float4*)(op + 4) = (float4){r[4], r[5], r[6], r[7]};
  }
}

// ---- correctness fallback (tiny ws), fp32 ----
__global__ void hqq_fallback_kernel(const float* __restrict__ x, const int* __restrict__ Wq,
                                    const float* __restrict__ scale, const float* __restrict__ zero,
                                    const float* __restrict__ bias, float* __restrict__ out)
{
  int idx = blockIdx.x * blockDim.x + threadIdx.x;
  int b = idx >> 13;
  int o = idx & 8191;
  int g = o >> 7, cc = o & 127;
  int r = g & 31;
  bool hi = (g < 32);
  const int*   wrow = Wq    + (size_t)r  * NGRP + (size_t)cc * IN_F;
  const float* srow = scale + (size_t)cc * IN_F;
  const float* zrow = zero  + (size_t)cc * IN_F;
  const float* xrow = x     + (size_t)b  * IN_F;
  float acc = 0.f;
  for (int k = 0; k < IN_F; ++k) {
    int v = wrow[k];
    float nib = (float)(hi ? (v >> 4) : (v & 15));
    acc += xrow[k] * ((nib - zrow[k]) * srow[k]);
  }
  out[idx] = acc + bias[o];
}

extern "C" void kernel_launch(void* const* d_in, const int* in_sizes, int n_in,
                              void* d_out, int out_size, void* d_ws, size_t ws_size,
                              hipStream_t stream) {
  const float* x     = (const float*)d_in[0];
  const int*   Wq    = (const int*)d_in[1];
  const float* scale = (const float*)d_in[2];
  const float* zero  = (const float*)d_in[3];
  const float* bias  = (const float*)d_in[4];
  float* out = (float*)d_out;

  const size_t xh_bytes   = (size_t)BATCH * IN_F * sizeof(ushort);        // 1 MB
  const size_t sz_bytes   = (size_t)NGRP * 4;                             // 4 MB
  const size_t part_bytes = (size_t)KS * BATCH * OUT_F * sizeof(float);   // 4 MB

  if (ws_size >= xh_bytes + sz_bytes + part_bytes) {
    ushort*   xh   = (ushort*)d_ws;
    uint32_t* szb  = (uint32_t*)((char*)d_ws + xh_bytes);
    float*    part = (float*)((char*)d_ws + xh_bytes + sz_bytes);
    pre_kernel<<<1536, 256, 0, stream>>>(x, xh, scale, zero, szb);
    hqq_gemm_kernel<<<128 * 2 * KS, 256, 0, stream>>>(Wq, szb, xh, part);
    reduce_kernel<<<OUT_F / 32, 256, 0, stream>>>(part, bias, out);
  } else {
    hqq_fallback_kernel<<<(BATCH * OUT_F) / 256, 256, 0, stream>>>(x, Wq, scale, zero, bias, out);
  }
}